// Round 12
// baseline (108.782 us; speedup 1.0000x reference)
//
#include <hip/hip_runtime.h>

#define IMG   224
#define IMG2  (IMG*IMG)
#define NN    27          // patches per dim
#define KK    256         // pixels per patch
#define EE    128
#define NSTRIP 28         // output 8-row strips
#define SCOLS 232         // strip row stride in elems (464 B)
#define RSTR  136         // rec row stride in elems (272 B, b128-aligned)

typedef float f32x4 __attribute__((ext_vector_type(4)));
typedef short s16x8 __attribute__((ext_vector_type(8)));

__device__ __forceinline__ unsigned short f2bf(float f) {
    unsigned int u = __float_as_uint(f);
    u = (u + 0x7fffu + ((u >> 16) & 1u)) >> 16;   // RNE (inputs finite)
    return (unsigned short)u;
}
__device__ __forceinline__ float bf2f(unsigned short u) {
    return __uint_as_float((unsigned int)u << 16);
}
// register-only packed cvt (RNE); single-instruction asm, no early-clobber hazard
__device__ __forceinline__ uint2 pack4(f32x4 r) {
    uint2 u;
    asm("v_cvt_pk_bf16_f32 %0, %1, %2" : "=v"(u.x) : "v"(r.x), "v"(r.y));
    asm("v_cvt_pk_bf16_f32 %0, %1, %2" : "=v"(u.y) : "v"(r.z), "v"(r.w));
    return u;
}

// M[c][k][j] = sum_e W_dec[c][k][e]*W_enc[c][e][j], packed in MFMA A-frag order:
// APK[c][kf(16)][jb(8)][lane(64)][i(8)] = bf16(M[kf*16+(lane&15)][jb*32+8*(lane>>4)+i])
// Also v[c][k] = b_dec[c][k] + sum_e W_dec[c][k][e]*b_enc[c][e].
__global__ void pack_M(const float* __restrict__ W_enc, const float* __restrict__ W_dec,
                       const float* __restrict__ b_enc, const float* __restrict__ b_dec,
                       unsigned short* __restrict__ APK, float* __restrict__ v) {
    int k = blockIdx.x, c = blockIdx.y, j = threadIdx.x;
    const float* wd = W_dec + ((size_t)c*KK + k)*EE;
    const float* we = W_enc + (size_t)c*EE*KK + j;
    float acc = 0.f;
    #pragma unroll 8
    for (int e = 0; e < EE; ++e) acc = fmaf(wd[e], we[(size_t)e*KK], acc);
    int kf = k >> 4, kr = k & 15, jb = j >> 5, g = (j >> 3) & 3, i = j & 7;
    APK[(size_t)c*65536 + (((kf*8 + jb)*64) + g*16 + kr)*8 + i] = f2bf(acc);

    __shared__ float pv[128];
    if (j < EE) pv[j] = wd[j] * b_enc[c*EE + j];
    __syncthreads();
    for (int off = 64; off > 0; off >>= 1) {
        if (j < off) pv[j] += pv[j + off];
        __syncthreads();
    }
    if (j == 0) v[c*KK + k] = pv[0] + b_dec[c*KK + k];
}

__global__ __launch_bounds__(256, 5)
void patch_ae_mfma(const float* __restrict__ x, const unsigned short* __restrict__ APK,
                   const float* __restrict__ v, float* __restrict__ out) {
    // bijective XCD swizzle: 5376 blocks = 8 XCDs x 672
    const int hid = blockIdx.x + NSTRIP*(blockIdx.y + 3*blockIdx.z);
    const int lid = (hid & 7)*672 + (hid >> 3);
    const int s  = lid % NSTRIP;
    const int t2 = lid / NSTRIP;
    const int c  = t2 % 3;
    const int b  = t2 / 3;

    const int tid  = threadIdx.x;
    const int lane = tid & 63, wave = tid >> 6;

    __shared__ __align__(16) unsigned short strip[24*SCOLS];   // 11136 B
    // rec slots: 0 = zero row, 1..27 = patches 0..26, 28 = zero row, 29 = dump (p>=27)
    __shared__ __align__(16) unsigned short rec[2][30][RSTR];  // 16320 B
    __shared__ __align__(16) float vsh[256];                   // 1024 B

    vsh[tid] = v[c*256 + tid];
    if (tid < RSTR) {   // zero rows (slots 0 and 28, both prows)
        rec[0][0][tid] = 0; rec[0][28][tid] = 0;
        rec[1][0][tid] = 0; rec[1][28][tid] = 0;
    }

    // wave constants
    const int prow    = wave >> 1;       // 0: ny=s (strip row 8), 1: ny=s-1 (strip row 0)
    const int kq      = wave & 1;
    const int rowbase = prow ? 0 : 8;
    const int kfbase  = prow*8 + kq*4;
    const int g = lane >> 4, lr = lane & 15;
    const s16x8* APKc = (const s16x8*)(APK + (size_t)c*65536);

    // depth-4 A prefetch: jb=0..3 issued before staging (latency hidden under stage)
    s16x8 aP0[4], aP1[4], aP2[4], aP3[4];
    #pragma unroll
    for (int f = 0; f < 4; ++f) aP0[f] = APKc[((kfbase + f)*8 + 0)*64 + lane];
    #pragma unroll
    for (int f = 0; f < 4; ++f) aP1[f] = APKc[((kfbase + f)*8 + 1)*64 + lane];
    #pragma unroll
    for (int f = 0; f < 4; ++f) aP2[f] = APKc[((kfbase + f)*8 + 2)*64 + lane];
    #pragma unroll
    for (int f = 0; f < 4; ++f) aP3[f] = APKc[((kfbase + f)*8 + 3)*64 + lane];

    // ---- stage input strip rows [8s-8, 8s+16), cols [0,224), f32 -> bf16 ----
    // chunk = 32B of f32 (8 px) -> one ds_write_b128; 28 chunks/row, 672 total
    {
        const float* xb = x + (size_t)(b*3 + c)*IMG2;
        const int ybase = 8*s - 8;
        #pragma unroll
        for (int it = 0; it < 3; ++it) {
            int ci = tid + it*256;
            if (ci < 672) {
                int r  = ci / 28;
                int cc = ci - r*28;
                int yr = ybase + r;
                float4 lo = make_float4(0.f,0.f,0.f,0.f), hi = lo;
                if ((unsigned)yr < IMG) {
                    const float4* src = (const float4*)(xb + (size_t)yr*IMG + cc*8);
                    lo = src[0]; hi = src[1];
                }
                uint2 u0 = pack4((f32x4){lo.x, lo.y, lo.z, lo.w});
                uint2 u1 = pack4((f32x4){hi.x, hi.y, hi.z, hi.w});
                *((uint4*)&strip[r*SCOLS + cc*8]) = make_uint4(u0.x, u0.y, u1.x, u1.y);
            }
        }
    }
    __syncthreads();

    // ---- MFMA with depth-4 A pipeline (static buffer names, fully unrolled) ----
    {
        f32x4 acc[4][2];
        #pragma unroll
        for (int f = 0; f < 4; ++f)
            #pragma unroll
            for (int pf = 0; pf < 2; ++pf)
                acc[f][pf] = (f32x4){0.f, 0.f, 0.f, 0.f};

        // pf1 column: patches 16+lr; lanes lr>=11 (p>=27 unused) clamped in-bounds
        const int c1 = (lr <= 10) ? (128 + 8*lr) : 208;

#define MFMA_STEP(JB, ABUF, RELOAD)                                                        \
        {                                                                                  \
            const int jy  = 2*(JB) + (g >> 1);                                             \
            const int jx0 = (g & 1)*8;                                                     \
            const unsigned short* srow = &strip[(rowbase + jy)*SCOLS + jx0];               \
            s16x8 bf0 = *((const s16x8*)&srow[8*lr]);                                      \
            s16x8 bf1 = *((const s16x8*)&srow[c1]);                                        \
            __builtin_amdgcn_s_setprio(1);                                                 \
            _Pragma("unroll")                                                              \
            for (int f = 0; f < 4; ++f) {                                                  \
                acc[f][0] = __builtin_amdgcn_mfma_f32_16x16x32_bf16(ABUF[f], bf0, acc[f][0], 0, 0, 0); \
                acc[f][1] = __builtin_amdgcn_mfma_f32_16x16x32_bf16(ABUF[f], bf1, acc[f][1], 0, 0, 0); \
            }                                                                              \
            __builtin_amdgcn_s_setprio(0);                                                 \
            if (RELOAD) {                                                                  \
                _Pragma("unroll")                                                          \
                for (int f = 0; f < 4; ++f)                                                \
                    ABUF[f] = APKc[((kfbase + f)*8 + ((JB)+4))*64 + lane];                 \
            }                                                                              \
        }

        MFMA_STEP(0, aP0, 1)
        MFMA_STEP(1, aP1, 1)
        MFMA_STEP(2, aP2, 1)
        MFMA_STEP(3, aP3, 1)
        MFMA_STEP(4, aP0, 0)
        MFMA_STEP(5, aP1, 0)
        MFMA_STEP(6, aP2, 0)
        MFMA_STEP(7, aP3, 0)
#undef MFMA_STEP

        // bias + bf16 store: patch p -> slot p+1 (p>=27 -> dump slot 29)
        #pragma unroll
        for (int f = 0; f < 4; ++f) {
            int klocal = kq*64 + f*16 + g*4;
            f32x4 bias = *((const f32x4*)&vsh[prow*128 + klocal]);
            #pragma unroll
            for (int pf = 0; pf < 2; ++pf) {
                f32x4 r = acc[f][pf] + bias;
                int pidx = pf*16 + lr + 1;
                if (pidx >= 28) pidx = 29;        // keep slot 28 = zeros
                *((uint2*)&rec[prow][pidx][klocal]) = pack4(r);
            }
        }
    }
    __syncthreads();

    // ---- epilogue: thread = (row ry, 8-col group q); 4 b128 reads, 2 dwordx4 stores ----
    if (tid < 224) {
        const int q  = tid % 28;           // col group: out cols 8q..8q+7
        const int ry = tid / 28;           // 0..7
        const int v1 = (q < 27);           // right patch (p1=q) exists
        const int v0 = (q > 0);            // left patch (p0=q-1) exists
        const int h0 = (s < NSTRIP-1);
        const int h1 = (s > 0);
        const int shift = (v0 & v1) + (h0 & h1);
        const float inv = __int_as_float(0x3f800000 - (shift << 23)); // exact 1/2^shift
        const int ro = ry*16;

        float sum[8];
        #pragma unroll
        for (int d = 0; d < 8; ++d) sum[d] = 0.f;
        if (h0) {
            s16x8 rr = *((const s16x8*)&rec[0][q+1][ro]);     // right: patch q (slot q+1)
            s16x8 ll = *((const s16x8*)&rec[0][q][ro + 8]);   // left: patch q-1 (slot q)
            #pragma unroll
            for (int d = 0; d < 8; ++d)
                sum[d] += bf2f((unsigned short)rr[d]) + bf2f((unsigned short)ll[d]);
        }
        if (h1) {
            s16x8 rr = *((const s16x8*)&rec[1][q+1][ro]);
            s16x8 ll = *((const s16x8*)&rec[1][q][ro + 8]);
            #pragma unroll
            for (int d = 0; d < 8; ++d)
                sum[d] += bf2f((unsigned short)rr[d]) + bf2f((unsigned short)ll[d]);
        }
        float* orow = out + (size_t)(b*3 + c)*IMG2 + (size_t)(8*s + ry)*IMG + 8*q;
        f32x4 o0 = {sum[0]*inv, sum[1]*inv, sum[2]*inv, sum[3]*inv};
        f32x4 o1 = {sum[4]*inv, sum[5]*inv, sum[6]*inv, sum[7]*inv};
        *((f32x4*)orow)       = o0;
        *((f32x4*)(orow + 4)) = o1;
    }
}

extern "C" void kernel_launch(void* const* d_in, const int* in_sizes, int n_in,
                              void* d_out, int out_size, void* d_ws, size_t ws_size,
                              hipStream_t stream) {
    (void)in_sizes; (void)n_in; (void)out_size; (void)ws_size;
    const float* x     = (const float*)d_in[0];
    const float* W_enc = (const float*)d_in[1];
    const float* b_enc = (const float*)d_in[2];
    const float* W_dec = (const float*)d_in[3];
    const float* b_dec = (const float*)d_in[4];
    float* out = (float*)d_out;

    float*          v   = (float*)d_ws;                          // 768 f32
    unsigned short* APK = (unsigned short*)((char*)d_ws + 4096); // 3 x 65536 bf16 = 384 KB

    pack_M<<<dim3(KK, 3), 256, 0, stream>>>(W_enc, W_dec, b_enc, b_dec, APK, v);
    patch_ae_mfma<<<dim3(NSTRIP, 3, 64), 256, 0, stream>>>(x, APK, v, out);
}

// Round 13
// 48.236 us; speedup vs baseline: 2.2552x; 2.2552x over previous
//
#include <hip/hip_runtime.h>

#define IMG   224
#define IMG2  (IMG*IMG)
#define NN    27          // patches per dim
#define KK    256         // pixels per patch
#define EE    128
#define NSTRIP 28         // output 8-row strips
#define SCOLS 232         // strip row stride in elems (464 B)
#define RSTR  136         // rec row stride in elems (272 B, b128-aligned)

typedef float f32x4 __attribute__((ext_vector_type(4)));
typedef short s16x8 __attribute__((ext_vector_type(8)));

__device__ __forceinline__ unsigned short f2bf(float f) {
    unsigned int u = __float_as_uint(f);
    u = (u + 0x7fffu + ((u >> 16) & 1u)) >> 16;   // RNE (inputs finite)
    return (unsigned short)u;
}
__device__ __forceinline__ float bf2f(unsigned short u) {
    return __uint_as_float((unsigned int)u << 16);
}
// register-only packed cvt (RNE); single-instruction asm, no early-clobber hazard
__device__ __forceinline__ uint2 pack4(f32x4 r) {
    uint2 u;
    asm("v_cvt_pk_bf16_f32 %0, %1, %2" : "=v"(u.x) : "v"(r.x), "v"(r.y));
    asm("v_cvt_pk_bf16_f32 %0, %1, %2" : "=v"(u.y) : "v"(r.z), "v"(r.w));
    return u;
}

// M[c][k][j] = sum_e W_dec[c][k][e]*W_enc[c][e][j], packed in MFMA A-frag order:
// APK[c][kf(16)][jb(8)][lane(64)][i(8)] = bf16(M[kf*16+(lane&15)][jb*32+8*(lane>>4)+i])
// Also v[c][k] = b_dec[c][k] + sum_e W_dec[c][k][e]*b_enc[c][e].
__global__ void pack_M(const float* __restrict__ W_enc, const float* __restrict__ W_dec,
                       const float* __restrict__ b_enc, const float* __restrict__ b_dec,
                       unsigned short* __restrict__ APK, float* __restrict__ v) {
    int k = blockIdx.x, c = blockIdx.y, j = threadIdx.x;
    const float* wd = W_dec + ((size_t)c*KK + k)*EE;
    const float* we = W_enc + (size_t)c*EE*KK + j;
    float acc = 0.f;
    #pragma unroll 8
    for (int e = 0; e < EE; ++e) acc = fmaf(wd[e], we[(size_t)e*KK], acc);
    int kf = k >> 4, kr = k & 15, jb = j >> 5, g = (j >> 3) & 3, i = j & 7;
    APK[(size_t)c*65536 + (((kf*8 + jb)*64) + g*16 + kr)*8 + i] = f2bf(acc);

    __shared__ float pv[128];
    if (j < EE) pv[j] = wd[j] * b_enc[c*EE + j];
    __syncthreads();
    for (int off = 64; off > 0; off >>= 1) {
        if (j < off) pv[j] += pv[j + off];
        __syncthreads();
    }
    if (j == 0) v[c*KK + k] = pv[0] + b_dec[c*KK + k];
}

__global__ __launch_bounds__(256, 4)
void patch_ae_mfma(const float* __restrict__ x, const unsigned short* __restrict__ APK,
                   const float* __restrict__ v, float* __restrict__ out) {
    // bijective XCD swizzle: 5376 blocks = 8 XCDs x 672
    const int hid = blockIdx.x + NSTRIP*(blockIdx.y + 3*blockIdx.z);
    const int lid = (hid & 7)*672 + (hid >> 3);
    const int s  = lid % NSTRIP;
    const int t2 = lid / NSTRIP;
    const int c  = t2 % 3;
    const int b  = t2 / 3;

    const int tid  = threadIdx.x;
    const int lane = tid & 63, wave = tid >> 6;

    __shared__ __align__(16) unsigned short strip[24*SCOLS];   // 11136 B
    // rec slots: 0 = zero row, 1..27 = patches 0..26, 28 = zero row, 29 = dump (p>=27)
    __shared__ __align__(16) unsigned short rec[2][30][RSTR];  // 16320 B
    __shared__ __align__(16) float vsh[256];                   // 1024 B

    vsh[tid] = v[c*256 + tid];
    if (tid < RSTR) {   // zero rows (slots 0 and 28, both prows)
        rec[0][0][tid] = 0; rec[0][28][tid] = 0;
        rec[1][0][tid] = 0; rec[1][28][tid] = 0;
    }

    // wave constants
    const int prow    = wave >> 1;       // 0: ny=s (strip row 8), 1: ny=s-1 (strip row 0)
    const int kq      = wave & 1;
    const int rowbase = prow ? 0 : 8;
    const int kfbase  = prow*8 + kq*4;
    const int g = lane >> 4, lr = lane & 15;
    const s16x8* APKc = (const s16x8*)(APK + (size_t)c*65536);

    // depth-2 A prefetch: jb=0 -> a0, jb=1 -> a1, issued before staging.
    // launch_bounds(256,4) gives 128-VGPR budget so BOTH buffers stay register-resident
    // (at (256,5)=102 the compiler sank them -> depth-0; r9/r12 post-mortem).
    s16x8 a0[4], a1[4];
    #pragma unroll
    for (int f = 0; f < 4; ++f) a0[f] = APKc[((kfbase + f)*8 + 0)*64 + lane];
    #pragma unroll
    for (int f = 0; f < 4; ++f) a1[f] = APKc[((kfbase + f)*8 + 1)*64 + lane];

    // ---- stage input strip rows [8s-8, 8s+16), cols [0,224), f32 -> bf16 ----
    // chunk = 32B of f32 (8 px) -> one ds_write_b128; 28 chunks/row, 672 total
    {
        const float* xb = x + (size_t)(b*3 + c)*IMG2;
        const int ybase = 8*s - 8;
        #pragma unroll
        for (int it = 0; it < 3; ++it) {
            int ci = tid + it*256;
            if (ci < 672) {
                int r  = ci / 28;
                int cc = ci - r*28;
                int yr = ybase + r;
                float4 lo = make_float4(0.f,0.f,0.f,0.f), hi = lo;
                if ((unsigned)yr < IMG) {
                    const float4* src = (const float4*)(xb + (size_t)yr*IMG + cc*8);
                    lo = src[0]; hi = src[1];
                }
                uint2 u0 = pack4((f32x4){lo.x, lo.y, lo.z, lo.w});
                uint2 u1 = pack4((f32x4){hi.x, hi.y, hi.z, hi.w});
                *((uint4*)&strip[r*SCOLS + cc*8]) = make_uint4(u0.x, u0.y, u1.x, u1.y);
            }
        }
    }
    __syncthreads();

    // ---- MFMA with depth-2 alternating-buffer A pipeline (static names, unrolled) ----
    {
        f32x4 acc[4][2];
        #pragma unroll
        for (int f = 0; f < 4; ++f)
            #pragma unroll
            for (int pf = 0; pf < 2; ++pf)
                acc[f][pf] = (f32x4){0.f, 0.f, 0.f, 0.f};

        // pf1 column: patches 16+lr; lanes lr>=11 (p>=27 unused) clamped in-bounds
        const int c1 = (lr <= 10) ? (128 + 8*lr) : 208;

#define MFMA_STEP(JB, ABUF, RELOAD)                                                        \
        {                                                                                  \
            const int jy  = 2*(JB) + (g >> 1);                                             \
            const int jx0 = (g & 1)*8;                                                     \
            const unsigned short* srow = &strip[(rowbase + jy)*SCOLS + jx0];               \
            s16x8 bf0 = *((const s16x8*)&srow[8*lr]);                                      \
            s16x8 bf1 = *((const s16x8*)&srow[c1]);                                        \
            __builtin_amdgcn_s_setprio(1);                                                 \
            _Pragma("unroll")                                                              \
            for (int f = 0; f < 4; ++f) {                                                  \
                acc[f][0] = __builtin_amdgcn_mfma_f32_16x16x32_bf16(ABUF[f], bf0, acc[f][0], 0, 0, 0); \
                acc[f][1] = __builtin_amdgcn_mfma_f32_16x16x32_bf16(ABUF[f], bf1, acc[f][1], 0, 0, 0); \
            }                                                                              \
            __builtin_amdgcn_s_setprio(0);                                                 \
            if (RELOAD) {                                                                  \
                _Pragma("unroll")                                                          \
                for (int f = 0; f < 4; ++f)                                                \
                    ABUF[f] = APKc[((kfbase + f)*8 + ((JB)+2))*64 + lane];                 \
            }                                                                              \
        }

        MFMA_STEP(0, a0, 1)
        MFMA_STEP(1, a1, 1)
        MFMA_STEP(2, a0, 1)
        MFMA_STEP(3, a1, 1)
        MFMA_STEP(4, a0, 1)
        MFMA_STEP(5, a1, 1)
        MFMA_STEP(6, a0, 0)
        MFMA_STEP(7, a1, 0)
#undef MFMA_STEP

        // bias + bf16 store: patch p -> slot p+1 (p>=27 -> dump slot 29)
        #pragma unroll
        for (int f = 0; f < 4; ++f) {
            int klocal = kq*64 + f*16 + g*4;
            f32x4 bias = *((const f32x4*)&vsh[prow*128 + klocal]);
            #pragma unroll
            for (int pf = 0; pf < 2; ++pf) {
                f32x4 r = acc[f][pf] + bias;
                int pidx = pf*16 + lr + 1;
                if (pidx >= 28) pidx = 29;        // keep slot 28 = zeros
                *((uint2*)&rec[prow][pidx][klocal]) = pack4(r);
            }
        }
    }
    __syncthreads();

    // ---- epilogue: thread = (row ry, 8-col group q); 4 b128 reads, 2 dwordx4 stores ----
    if (tid < 224) {
        const int q  = tid % 28;           // col group: out cols 8q..8q+7
        const int ry = tid / 28;           // 0..7
        const int v1 = (q < 27);           // right patch (p1=q) exists
        const int v0 = (q > 0);            // left patch (p0=q-1) exists
        const int h0 = (s < NSTRIP-1);
        const int h1 = (s > 0);
        const int shift = (v0 & v1) + (h0 & h1);
        const float inv = __int_as_float(0x3f800000 - (shift << 23)); // exact 1/2^shift
        const int ro = ry*16;

        float sum[8];
        #pragma unroll
        for (int d = 0; d < 8; ++d) sum[d] = 0.f;
        if (h0) {
            s16x8 rr = *((const s16x8*)&rec[0][q+1][ro]);     // right: patch q (slot q+1)
            s16x8 ll = *((const s16x8*)&rec[0][q][ro + 8]);   // left: patch q-1 (slot q)
            #pragma unroll
            for (int d = 0; d < 8; ++d)
                sum[d] += bf2f((unsigned short)rr[d]) + bf2f((unsigned short)ll[d]);
        }
        if (h1) {
            s16x8 rr = *((const s16x8*)&rec[1][q+1][ro]);
            s16x8 ll = *((const s16x8*)&rec[1][q][ro + 8]);
            #pragma unroll
            for (int d = 0; d < 8; ++d)
                sum[d] += bf2f((unsigned short)rr[d]) + bf2f((unsigned short)ll[d]);
        }
        float* orow = out + (size_t)(b*3 + c)*IMG2 + (size_t)(8*s + ry)*IMG + 8*q;
        f32x4 o0 = {sum[0]*inv, sum[1]*inv, sum[2]*inv, sum[3]*inv};
        f32x4 o1 = {sum[4]*inv, sum[5]*inv, sum[6]*inv, sum[7]*inv};
        *((f32x4*)orow)       = o0;
        *((f32x4*)(orow + 4)) = o1;
    }
}

extern "C" void kernel_launch(void* const* d_in, const int* in_sizes, int n_in,
                              void* d_out, int out_size, void* d_ws, size_t ws_size,
                              hipStream_t stream) {
    (void)in_sizes; (void)n_in; (void)out_size; (void)ws_size;
    const float* x     = (const float*)d_in[0];
    const float* W_enc = (const float*)d_in[1];
    const float* b_enc = (const float*)d_in[2];
    const float* W_dec = (const float*)d_in[3];
    const float* b_dec = (const float*)d_in[4];
    float* out = (float*)d_out;

    float*          v   = (float*)d_ws;                          // 768 f32
    unsigned short* APK = (unsigned short*)((char*)d_ws + 4096); // 3 x 65536 bf16 = 384 KB

    pack_M<<<dim3(KK, 3), 256, 0, stream>>>(W_enc, W_dec, b_enc, b_dec, APK, v);
    patch_ae_mfma<<<dim3(NSTRIP, 3, 64), 256, 0, stream>>>(x, APK, v, out);
}

// Round 14
// 47.892 us; speedup vs baseline: 2.2714x; 1.0072x over previous
//
#include <hip/hip_runtime.h>

#define IMG   224
#define IMG2  (IMG*IMG)
#define NN    27          // patches per dim
#define KK    256         // pixels per patch
#define EE    128
#define NSTRIP 28         // output 8-row strips
#define SCOLS 232         // strip row stride in elems (464 B)
#define RSTR  136         // rec row stride in elems (272 B, b128-aligned)

typedef float f32x4 __attribute__((ext_vector_type(4)));
typedef short s16x8 __attribute__((ext_vector_type(8)));

__device__ __forceinline__ unsigned short f2bf(float f) {
    unsigned int u = __float_as_uint(f);
    u = (u + 0x7fffu + ((u >> 16) & 1u)) >> 16;   // RNE (inputs finite)
    return (unsigned short)u;
}
__device__ __forceinline__ float bf2f(unsigned short u) {
    return __uint_as_float((unsigned int)u << 16);
}
// register-only packed cvt (RNE); single-instruction asm, no early-clobber hazard
__device__ __forceinline__ uint2 pack4(f32x4 r) {
    uint2 u;
    asm("v_cvt_pk_bf16_f32 %0, %1, %2" : "=v"(u.x) : "v"(r.x), "v"(r.y));
    asm("v_cvt_pk_bf16_f32 %0, %1, %2" : "=v"(u.y) : "v"(r.z), "v"(r.w));
    return u;
}

// M[c][k][j] = sum_e W_dec[c][k][e]*W_enc[c][e][j], packed in MFMA A-frag order:
// APK[c][kf(16)][jb(8)][lane(64)][i(8)] = bf16(M[kf*16+(lane&15)][jb*32+8*(lane>>4)+i])
// Also v[c][k] = b_dec[c][k] + sum_e W_dec[c][k][e]*b_enc[c][e].
__global__ void pack_M(const float* __restrict__ W_enc, const float* __restrict__ W_dec,
                       const float* __restrict__ b_enc, const float* __restrict__ b_dec,
                       unsigned short* __restrict__ APK, float* __restrict__ v) {
    int k = blockIdx.x, c = blockIdx.y, j = threadIdx.x;
    const float* wd = W_dec + ((size_t)c*KK + k)*EE;
    const float* we = W_enc + (size_t)c*EE*KK + j;
    float acc = 0.f;
    #pragma unroll 8
    for (int e = 0; e < EE; ++e) acc = fmaf(wd[e], we[(size_t)e*KK], acc);
    int kf = k >> 4, kr = k & 15, jb = j >> 5, g = (j >> 3) & 3, i = j & 7;
    APK[(size_t)c*65536 + (((kf*8 + jb)*64) + g*16 + kr)*8 + i] = f2bf(acc);

    __shared__ float pv[128];
    if (j < EE) pv[j] = wd[j] * b_enc[c*EE + j];
    __syncthreads();
    for (int off = 64; off > 0; off >>= 1) {
        if (j < off) pv[j] += pv[j + off];
        __syncthreads();
    }
    if (j == 0) v[c*KK + k] = pv[0] + b_dec[c*KK + k];
}

__global__ __launch_bounds__(256, 4)
void patch_ae_mfma(const float* __restrict__ x, const unsigned short* __restrict__ APK,
                   const float* __restrict__ v, float* __restrict__ out) {
    // bijective XCD swizzle: 5376 blocks = 8 XCDs x 672
    const int hid = blockIdx.x + NSTRIP*(blockIdx.y + 3*blockIdx.z);
    const int lid = (hid & 7)*672 + (hid >> 3);
    const int s  = lid % NSTRIP;
    const int t2 = lid / NSTRIP;
    const int c  = t2 % 3;
    const int b  = t2 / 3;

    const int tid  = threadIdx.x;
    const int lane = tid & 63, wave = tid >> 6;

    __shared__ __align__(16) unsigned short strip[24*SCOLS];   // 11136 B
    // rec slots: 0 = zero row, 1..27 = patches 0..26, 28 = zero row, 29 = dump (p>=27)
    __shared__ __align__(16) unsigned short rec[2][30][RSTR];  // 16320 B
    __shared__ __align__(16) float vsh[256];                   // 1024 B

    vsh[tid] = v[c*256 + tid];
    if (tid < RSTR) {   // zero rows (slots 0 and 28, both prows)
        rec[0][0][tid] = 0; rec[0][28][tid] = 0;
        rec[1][0][tid] = 0; rec[1][28][tid] = 0;
    }

    // wave constants
    const int prow    = wave >> 1;       // 0: ny=s (strip row 8), 1: ny=s-1 (strip row 0)
    const int kq      = wave & 1;
    const int rowbase = prow ? 0 : 8;
    const int kfbase  = prow*8 + kq*4;
    const int g = lane >> 4, lr = lane & 15;
    const int jx0 = (g & 1)*8;
    // pf1 column: patches 16+lr; lanes lr>=11 (p>=27 unused) clamped in-bounds
    const int c1 = (lr <= 10) ? (128 + 8*lr) : 208;

    // ---- hand-pipelined A stream: SGPR base + per-f voffset, asm loads ----
    // byte addr of frag(f,jb,lane) = APKc + kfbase*8192 + f*8192 + jb*1024 + lane*16
    const int kfu = __builtin_amdgcn_readfirstlane(kfbase);          // uniform -> SGPR
    const char* sbase = (const char*)(APK + (size_t)c*65536) + (size_t)kfu*8192;
    const int voff0 = lane*16;
    const int voff1 = voff0 + 8192;
    const int voff2 = voff0 + 16384;
    const int voff3 = voff0 + 24576;

#define AISSUE(DST, VOFF, OFFSTR)                                   \
    asm volatile("global_load_dwordx4 %0, %1, %2 offset:" OFFSTR    \
                 : "=v"(DST) : "v"(VOFF), "s"(sbase));

    s16x8 aA0, aA1, aA2, aA3, aB0, aB1, aB2, aB3;
    // prologue: jb0 -> aA*, jb1 -> aB* (8 loads in flight across staging)
    AISSUE(aA0, voff0, "0")    AISSUE(aA1, voff1, "0")
    AISSUE(aA2, voff2, "0")    AISSUE(aA3, voff3, "0")
    AISSUE(aB0, voff0, "1024") AISSUE(aB1, voff1, "1024")
    AISSUE(aB2, voff2, "1024") AISSUE(aB3, voff3, "1024")

    // ---- stage input strip rows [8s-8, 8s+16), cols [0,224), f32 -> bf16 ----
    // chunk = 32B of f32 (8 px) -> one ds_write_b128; 28 chunks/row, 672 total
    {
        const float* xb = x + (size_t)(b*3 + c)*IMG2;
        const int ybase = 8*s - 8;
        #pragma unroll
        for (int it = 0; it < 3; ++it) {
            int ci = tid + it*256;
            if (ci < 672) {
                int r  = ci / 28;
                int cc = ci - r*28;
                int yr = ybase + r;
                float4 lo = make_float4(0.f,0.f,0.f,0.f), hi = lo;
                if ((unsigned)yr < IMG) {
                    const float4* src = (const float4*)(xb + (size_t)yr*IMG + cc*8);
                    lo = src[0]; hi = src[1];
                }
                uint2 u0 = pack4((f32x4){lo.x, lo.y, lo.z, lo.w});
                uint2 u1 = pack4((f32x4){hi.x, hi.y, hi.z, hi.w});
                *((uint4*)&strip[r*SCOLS + cc*8]) = make_uint4(u0.x, u0.y, u1.x, u1.y);
            }
        }
    }
    __syncthreads();   // note: barrier drains vmcnt -> prologue loads complete here

    // ---- MFMA with forced depth-2 pipeline: counted vmcnt, never sunk ----
    {
        f32x4 acc[4][2];
        #pragma unroll
        for (int f = 0; f < 4; ++f)
            #pragma unroll
            for (int pf = 0; pf < 2; ++pf)
                acc[f][pf] = (f32x4){0.f, 0.f, 0.f, 0.f};

#define MFMA2(AF, B0, B1, F)                                                         \
        acc[F][0] = __builtin_amdgcn_mfma_f32_16x16x32_bf16(AF, B0, acc[F][0], 0, 0, 0); \
        acc[F][1] = __builtin_amdgcn_mfma_f32_16x16x32_bf16(AF, B1, acc[F][1], 0, 0, 0);

#define MSTEP(JB, A0, A1, A2, A3, WAITSTR)                                           \
        {                                                                            \
            const int jy = 2*(JB) + (g >> 1);                                        \
            const unsigned short* srow = &strip[(rowbase + jy)*SCOLS + jx0];         \
            s16x8 bf0 = *((const s16x8*)&srow[8*lr]);                                \
            s16x8 bf1 = *((const s16x8*)&srow[c1]);                                  \
            asm volatile("s_waitcnt vmcnt(" WAITSTR ")");                            \
            __builtin_amdgcn_sched_barrier(0);                                       \
            __builtin_amdgcn_s_setprio(1);                                           \
            MFMA2(A0, bf0, bf1, 0) MFMA2(A1, bf0, bf1, 1)                            \
            MFMA2(A2, bf0, bf1, 2) MFMA2(A3, bf0, bf1, 3)                            \
            __builtin_amdgcn_s_setprio(0);                                           \
        }

        // steady state: 8 outstanding; wait-to-4 retires current jb's 4 frags
        MSTEP(0, aA0, aA1, aA2, aA3, "4")
        AISSUE(aA0, voff0, "2048")        AISSUE(aA1, voff1, "2048")      // jb2
        AISSUE(aA2, voff2, "2048")        AISSUE(aA3, voff3, "2048")
        MSTEP(1, aB0, aB1, aB2, aB3, "4")
        AISSUE(aB0, voff0, "3072")        AISSUE(aB1, voff1, "3072")      // jb3
        AISSUE(aB2, voff2, "3072")        AISSUE(aB3, voff3, "3072")
        MSTEP(2, aA0, aA1, aA2, aA3, "4")
        AISSUE(aA0, voff0 + 4096, "0")    AISSUE(aA1, voff1 + 4096, "0")  // jb4
        AISSUE(aA2, voff2 + 4096, "0")    AISSUE(aA3, voff3 + 4096, "0")
        MSTEP(3, aB0, aB1, aB2, aB3, "4")
        AISSUE(aB0, voff0 + 4096, "1024") AISSUE(aB1, voff1 + 4096, "1024") // jb5
        AISSUE(aB2, voff2 + 4096, "1024") AISSUE(aB3, voff3 + 4096, "1024")
        MSTEP(4, aA0, aA1, aA2, aA3, "4")
        AISSUE(aA0, voff0 + 4096, "2048") AISSUE(aA1, voff1 + 4096, "2048") // jb6
        AISSUE(aA2, voff2 + 4096, "2048") AISSUE(aA3, voff3 + 4096, "2048")
        MSTEP(5, aB0, aB1, aB2, aB3, "4")
        AISSUE(aB0, voff0 + 4096, "3072") AISSUE(aB1, voff1 + 4096, "3072") // jb7
        AISSUE(aB2, voff2 + 4096, "3072") AISSUE(aB3, voff3 + 4096, "3072")
        MSTEP(6, aA0, aA1, aA2, aA3, "4")
        MSTEP(7, aB0, aB1, aB2, aB3, "0")
#undef MSTEP
#undef MFMA2
#undef AISSUE

        // bias + bf16 store: patch p -> slot p+1 (p>=27 -> dump slot 29)
        #pragma unroll
        for (int f = 0; f < 4; ++f) {
            int klocal = kq*64 + f*16 + g*4;
            f32x4 bias = *((const f32x4*)&vsh[prow*128 + klocal]);
            #pragma unroll
            for (int pf = 0; pf < 2; ++pf) {
                f32x4 r = acc[f][pf] + bias;
                int pidx = pf*16 + lr + 1;
                if (pidx >= 28) pidx = 29;        // keep slot 28 = zeros
                *((uint2*)&rec[prow][pidx][klocal]) = pack4(r);
            }
        }
    }
    __syncthreads();

    // ---- epilogue: thread = (row ry, 8-col group q); 4 b128 reads, 2 dwordx4 stores ----
    if (tid < 224) {
        const int q  = tid % 28;           // col group: out cols 8q..8q+7
        const int ry = tid / 28;           // 0..7
        const int v1 = (q < 27);           // right patch (p1=q) exists
        const int v0 = (q > 0);            // left patch (p0=q-1) exists
        const int h0 = (s < NSTRIP-1);
        const int h1 = (s > 0);
        const int shift = (v0 & v1) + (h0 & h1);
        const float inv = __int_as_float(0x3f800000 - (shift << 23)); // exact 1/2^shift
        const int ro = ry*16;

        float sum[8];
        #pragma unroll
        for (int d = 0; d < 8; ++d) sum[d] = 0.f;
        if (h0) {
            s16x8 rr = *((const s16x8*)&rec[0][q+1][ro]);     // right: patch q (slot q+1)
            s16x8 ll = *((const s16x8*)&rec[0][q][ro + 8]);   // left: patch q-1 (slot q)
            #pragma unroll
            for (int d = 0; d < 8; ++d)
                sum[d] += bf2f((unsigned short)rr[d]) + bf2f((unsigned short)ll[d]);
        }
        if (h1) {
            s16x8 rr = *((const s16x8*)&rec[1][q+1][ro]);
            s16x8 ll = *((const s16x8*)&rec[1][q][ro + 8]);
            #pragma unroll
            for (int d = 0; d < 8; ++d)
                sum[d] += bf2f((unsigned short)rr[d]) + bf2f((unsigned short)ll[d]);
        }
        float* orow = out + (size_t)(b*3 + c)*IMG2 + (size_t)(8*s + ry)*IMG + 8*q;
        f32x4 o0 = {sum[0]*inv, sum[1]*inv, sum[2]*inv, sum[3]*inv};
        f32x4 o1 = {sum[4]*inv, sum[5]*inv, sum[6]*inv, sum[7]*inv};
        *((f32x4*)orow)       = o0;
        *((f32x4*)(orow + 4)) = o1;
    }
}

extern "C" void kernel_launch(void* const* d_in, const int* in_sizes, int n_in,
                              void* d_out, int out_size, void* d_ws, size_t ws_size,
                              hipStream_t stream) {
    (void)in_sizes; (void)n_in; (void)out_size; (void)ws_size;
    const float* x     = (const float*)d_in[0];
    const float* W_enc = (const float*)d_in[1];
    const float* b_enc = (const float*)d_in[2];
    const float* W_dec = (const float*)d_in[3];
    const float* b_dec = (const float*)d_in[4];
    float* out = (float*)d_out;

    float*          v   = (float*)d_ws;                          // 768 f32
    unsigned short* APK = (unsigned short*)((char*)d_ws + 4096); // 3 x 65536 bf16 = 384 KB

    pack_M<<<dim3(KK, 3), 256, 0, stream>>>(W_enc, W_dec, b_enc, b_dec, APK, v);
    patch_ae_mfma<<<dim3(NSTRIP, 3, 64), 256, 0, stream>>>(x, APK, v, out);
}

// Round 16
// 42.360 us; speedup vs baseline: 2.5680x; 1.1306x over previous
//
#include <hip/hip_runtime.h>

#define IMG   224
#define IMG2  (IMG*IMG)
#define NN    27          // patches per dim
#define KK    256         // pixels per patch
#define EE    128
#define SCOLS 232         // ring row stride in elems (464 B)
#define RSTR  136         // rec row stride in elems (272 B, b128-aligned)

typedef float f32x4 __attribute__((ext_vector_type(4)));
typedef short s16x8 __attribute__((ext_vector_type(8)));

__device__ __forceinline__ unsigned short f2bf(float f) {
    unsigned int u = __float_as_uint(f);
    u = (u + 0x7fffu + ((u >> 16) & 1u)) >> 16;   // RNE (inputs finite)
    return (unsigned short)u;
}
__device__ __forceinline__ float bf2f(unsigned short u) {
    return __uint_as_float((unsigned int)u << 16);
}
// register-only packed cvt (RNE); single-instruction asm, no early-clobber hazard
__device__ __forceinline__ uint2 pack4(f32x4 r) {
    uint2 u;
    asm("v_cvt_pk_bf16_f32 %0, %1, %2" : "=v"(u.x) : "v"(r.x), "v"(r.y));
    asm("v_cvt_pk_bf16_f32 %0, %1, %2" : "=v"(u.y) : "v"(r.z), "v"(r.w));
    return u;
}

// M[c][k][j] = sum_e W_dec[c][k][e]*W_enc[c][e][j], packed in MFMA A-frag order:
// APK[c][kf(16)][jb(8)][lane(64)][i(8)] = bf16(M[kf*16+(lane&15)][jb*32+8*(lane>>4)+i])
// Also v[c][k] = b_dec[c][k] + sum_e W_dec[c][k][e]*b_enc[c][e].
__global__ void pack_M(const float* __restrict__ W_enc, const float* __restrict__ W_dec,
                       const float* __restrict__ b_enc, const float* __restrict__ b_dec,
                       unsigned short* __restrict__ APK, float* __restrict__ v) {
    int k = blockIdx.x, c = blockIdx.y, j = threadIdx.x;
    const float* wd = W_dec + ((size_t)c*KK + k)*EE;
    const float* we = W_enc + (size_t)c*EE*KK + j;
    float acc = 0.f;
    #pragma unroll 8
    for (int e = 0; e < EE; ++e) acc = fmaf(wd[e], we[(size_t)e*KK], acc);
    int kf = k >> 4, kr = k & 15, jb = j >> 5, g = (j >> 3) & 3, i = j & 7;
    APK[(size_t)c*65536 + (((kf*8 + jb)*64) + g*16 + kr)*8 + i] = f2bf(acc);

    __shared__ float pv[128];
    if (j < EE) pv[j] = wd[j] * b_enc[c*EE + j];
    __syncthreads();
    for (int off = 64; off > 0; off >>= 1) {
        if (j < off) pv[j] += pv[j + off];
        __syncthreads();
    }
    if (j == 0) v[c*KK + k] = pv[0] + b_dec[c*KK + k];
}

// Block = (b, c, quarter q): strips 7q..7q+6 processed in a loop.
// A (32 frags = 128 VGPR) asm-pinned once per block; input staged via 32-row LDS ring.
__global__ __launch_bounds__(256, 2)
void patch_ae_loop(const float* __restrict__ x, const unsigned short* __restrict__ APK,
                   const float* __restrict__ v, float* __restrict__ out) {
    // bijective XCD swizzle: 768 blocks = 8 XCDs x 96
    const int hid = blockIdx.x;
    const int lid = (hid & 7)*96 + (hid >> 3);
    const int q   = lid & 3;
    const int t2  = lid >> 2;       // 0..191
    const int c   = t2 % 3;
    const int b   = t2 / 3;
    const int s0  = 7*q;

    const int tid  = threadIdx.x;
    const int lane = tid & 63, wave = tid >> 6;

    __shared__ __align__(16) unsigned short ring[32*SCOLS];    // 14848 B (4 groups x 8 rows)
    // rec slots: 0 = zero row, 1..27 = patches 0..26, 28 = zero row, 29 = dump (p>=27)
    __shared__ __align__(16) unsigned short rec[2][30][RSTR];  // 16320 B
    __shared__ __align__(16) float vsh[256];                   // 1024 B

    vsh[tid] = v[c*256 + tid];
    if (tid < RSTR) {   // zero rows (slots 0 and 28, both prows)
        rec[0][0][tid] = 0; rec[0][28][tid] = 0;
        rec[1][0][tid] = 0; rec[1][28][tid] = 0;
    }

    // wave constants
    const int prow   = wave >> 1;      // 0: ny=s, 1: ny=s-1
    const int kq     = wave & 1;
    const int kfbase = prow*8 + kq*4;
    const int g = lane >> 4, lr = lane & 15;
    const int jx0 = (g & 1)*8;
    const int c1 = (lr <= 10) ? (128 + 8*lr) : 208;   // pf1 col, clamped (p>=27 unused)
    const int rowoff = prow ? -8 : 0;

    // ---- A: 32 frags loaded ONCE, asm-pinned (cannot be sunk/re-materialized) ----
    // global_load offset imm is 13-bit SIGNED (max 4095): use voffset regs for +4096.
    const int kfu = __builtin_amdgcn_readfirstlane(kfbase);
    const char* abase = (const char*)(APK + (size_t)c*65536) + (size_t)kfu*8192;
    const int vf0 = lane*16,        vf0b = vf0 + 4096;
    const int vf1 = vf0 + 8192,     vf1b = vf1 + 4096;
    const int vf2 = vf0 + 16384,    vf2b = vf2 + 4096;
    const int vf3 = vf0 + 24576,    vf3b = vf3 + 4096;

#define ALD(VAR, VOFF, OFFSTR)                                      \
    asm volatile("global_load_dwordx4 %0, %1, %2 offset:" OFFSTR    \
                 : "=v"(VAR) : "v"(VOFF), "s"(abase));

    s16x8 a0_0,a0_1,a0_2,a0_3,a0_4,a0_5,a0_6,a0_7;
    s16x8 a1_0,a1_1,a1_2,a1_3,a1_4,a1_5,a1_6,a1_7;
    s16x8 a2_0,a2_1,a2_2,a2_3,a2_4,a2_5,a2_6,a2_7;
    s16x8 a3_0,a3_1,a3_2,a3_3,a3_4,a3_5,a3_6,a3_7;
    ALD(a0_0, vf0,  "0")    ALD(a0_1, vf0,  "1024") ALD(a0_2, vf0,  "2048") ALD(a0_3, vf0,  "3072")
    ALD(a0_4, vf0b, "0")    ALD(a0_5, vf0b, "1024") ALD(a0_6, vf0b, "2048") ALD(a0_7, vf0b, "3072")
    ALD(a1_0, vf1,  "0")    ALD(a1_1, vf1,  "1024") ALD(a1_2, vf1,  "2048") ALD(a1_3, vf1,  "3072")
    ALD(a1_4, vf1b, "0")    ALD(a1_5, vf1b, "1024") ALD(a1_6, vf1b, "2048") ALD(a1_7, vf1b, "3072")
    ALD(a2_0, vf2,  "0")    ALD(a2_1, vf2,  "1024") ALD(a2_2, vf2,  "2048") ALD(a2_3, vf2,  "3072")
    ALD(a2_4, vf2b, "0")    ALD(a2_5, vf2b, "1024") ALD(a2_6, vf2b, "2048") ALD(a2_7, vf2b, "3072")
    ALD(a3_0, vf3,  "0")    ALD(a3_1, vf3,  "1024") ALD(a3_2, vf3,  "2048") ALD(a3_3, vf3,  "3072")
    ALD(a3_4, vf3b, "0")    ALD(a3_5, vf3b, "1024") ALD(a3_6, vf3b, "2048") ALD(a3_7, vf3b, "3072")
#undef ALD

    const float* xb = x + (size_t)(b*3 + c)*IMG2;

    // ---- prologue staging: groups s0-1, s0, s0+1 (24 rows, row-clamped) ----
    #pragma unroll
    for (int it = 0; it < 3; ++it) {
        int ci = tid + it*256;
        if (ci < 672) {
            int r  = ci / 28, cc = ci - (ci/28)*28;
            int ar = 8*s0 - 8 + r;                 // absolute image row (may be OOB)
            int yr = ar < 0 ? 0 : (ar > 223 ? 223 : ar);
            const float4* src = (const float4*)(xb + (size_t)yr*IMG + cc*8);
            float4 lo = src[0], hi = src[1];
            uint2 u0 = pack4((f32x4){lo.x, lo.y, lo.z, lo.w});
            uint2 u1 = pack4((f32x4){hi.x, hi.y, hi.z, hi.w});
            *((uint4*)&ring[(ar & 31)*SCOLS + cc*8]) = make_uint4(u0.x, u0.y, u1.x, u1.y);
        }
    }
    __syncthreads();
    asm volatile("s_waitcnt vmcnt(0)");     // A frags resident before first MFMA
    __builtin_amdgcn_sched_barrier(0);

    // per-thread staging constants (tid<224: one 8-px chunk per row-group)
    const int rr  = tid / 28;
    const int cc2 = tid - 28*(tid/28);

    // epilogue constants
    const int eq  = tid % 28, ery = tid / 28;       // col group, row (tid<224)
    const int ev1 = (eq < 27), ev0 = (eq > 0);
    const int ero = ery*16;

#define MFMA2(AF, B0, B1, F)                                                             \
        acc[F][0] = __builtin_amdgcn_mfma_f32_16x16x32_bf16(AF, B0, acc[F][0], 0, 0, 0); \
        acc[F][1] = __builtin_amdgcn_mfma_f32_16x16x32_bf16(AF, B1, acc[F][1], 0, 0, 0);

#define MSTEP(JB, A0, A1, A2, A3)                                                    \
        {                                                                            \
            const int jy = 2*(JB) + (g >> 1);                                        \
            const unsigned short* srow = &ring[((rowb + jy) & 31)*SCOLS + jx0];      \
            s16x8 bf0 = *((const s16x8*)&srow[8*lr]);                                \
            s16x8 bf1 = *((const s16x8*)&srow[c1]);                                  \
            __builtin_amdgcn_s_setprio(1);                                           \
            MFMA2(A0, bf0, bf1, 0) MFMA2(A1, bf0, bf1, 1)                            \
            MFMA2(A2, bf0, bf1, 2) MFMA2(A3, bf0, bf1, 3)                            \
            __builtin_amdgcn_s_setprio(0);                                           \
        }

    #pragma unroll 1
    for (int s = s0; s < s0 + 7; ++s) {
        // 1. issue prefetch of group s+2 (8 rows; lands in regs, hides under MFMA)
        f32x4 ga0, ga1;
        if (tid < 224) {
            int yr = 8*(s+2) + rr; if (yr > 223) yr = 223;   // clamp: garbage rows unread
            int voffx = yr*(IMG*4) + cc2*32;
            asm volatile("global_load_dwordx4 %0, %1, %2"           : "=v"(ga0) : "v"(voffx), "s"(xb));
            asm volatile("global_load_dwordx4 %0, %1, %2 offset:16" : "=v"(ga1) : "v"(voffx), "s"(xb));
        }

        // 2. MFMA over strip s (A pinned in regs, B from ring)
        f32x4 acc[4][2];
        #pragma unroll
        for (int f = 0; f < 4; ++f)
            #pragma unroll
            for (int pf = 0; pf < 2; ++pf)
                acc[f][pf] = (f32x4){0.f, 0.f, 0.f, 0.f};
        const int rowb = 8*s + rowoff;
        MSTEP(0, a0_0, a1_0, a2_0, a3_0)
        MSTEP(1, a0_1, a1_1, a2_1, a3_1)
        MSTEP(2, a0_2, a1_2, a2_2, a3_2)
        MSTEP(3, a0_3, a1_3, a2_3, a3_3)
        MSTEP(4, a0_4, a1_4, a2_4, a3_4)
        MSTEP(5, a0_5, a1_5, a2_5, a3_5)
        MSTEP(6, a0_6, a1_6, a2_6, a3_6)
        MSTEP(7, a0_7, a1_7, a2_7, a3_7)

        // 3. bias + bf16 rec store: patch p -> slot p+1 (p>=27 -> dump slot 29)
        #pragma unroll
        for (int f = 0; f < 4; ++f) {
            int klocal = kq*64 + f*16 + g*4;
            f32x4 bias = *((const f32x4*)&vsh[prow*128 + klocal]);
            #pragma unroll
            for (int pf = 0; pf < 2; ++pf) {
                f32x4 r = acc[f][pf] + bias;
                int pidx = pf*16 + lr + 1;
                if (pidx >= 28) pidx = 29;
                *((uint2*)&rec[prow][pidx][klocal]) = pack4(r);
            }
        }
        __syncthreads();   // 4. rec ready; ring reads of strip s done

        // 5. write prefetched group s+2 into ring (slot disjoint from groups s..s+2 reads)
        if (tid < 224) {
            asm volatile("s_waitcnt vmcnt(0)");
            __builtin_amdgcn_sched_barrier(0);
            uint2 u0 = pack4(ga0);
            uint2 u1 = pack4(ga1);
            int ar2 = 8*(s+2) + rr;
            *((uint4*)&ring[(ar2 & 31)*SCOLS + cc2*8]) = make_uint4(u0.x, u0.y, u1.x, u1.y);
        }

        // 6. epilogue for strip s: 4 b128 rec reads, 2 dwordx4 stores per thread
        if (tid < 224) {
            const int h0 = (s < 27);
            const int h1 = (s > 0);
            const int shift = (ev0 & ev1) + (h0 & h1);
            const float inv = __int_as_float(0x3f800000 - (shift << 23)); // exact 1/2^shift
            float sum[8];
            #pragma unroll
            for (int d = 0; d < 8; ++d) sum[d] = 0.f;
            if (h0) {
                s16x8 rrv = *((const s16x8*)&rec[0][eq+1][ero]);
                s16x8 llv = *((const s16x8*)&rec[0][eq][ero + 8]);
                #pragma unroll
                for (int d = 0; d < 8; ++d)
                    sum[d] += bf2f((unsigned short)rrv[d]) + bf2f((unsigned short)llv[d]);
            }
            if (h1) {
                s16x8 rrv = *((const s16x8*)&rec[1][eq+1][ero]);
                s16x8 llv = *((const s16x8*)&rec[1][eq][ero + 8]);
                #pragma unroll
                for (int d = 0; d < 8; ++d)
                    sum[d] += bf2f((unsigned short)rrv[d]) + bf2f((unsigned short)llv[d]);
            }
            float* orow = out + (size_t)(b*3 + c)*IMG2 + (size_t)(8*s + ery)*IMG + 8*eq;
            f32x4 o0 = {sum[0]*inv, sum[1]*inv, sum[2]*inv, sum[3]*inv};
            f32x4 o1 = {sum[4]*inv, sum[5]*inv, sum[6]*inv, sum[7]*inv};
            *((f32x4*)orow)       = o0;
            *((f32x4*)(orow + 4)) = o1;
        }
        __syncthreads();   // 7. rec reads done + ring writes visible before next iter
    }
#undef MSTEP
#undef MFMA2
}

extern "C" void kernel_launch(void* const* d_in, const int* in_sizes, int n_in,
                              void* d_out, int out_size, void* d_ws, size_t ws_size,
                              hipStream_t stream) {
    (void)in_sizes; (void)n_in; (void)out_size; (void)ws_size;
    const float* x     = (const float*)d_in[0];
    const float* W_enc = (const float*)d_in[1];
    const float* b_enc = (const float*)d_in[2];
    const float* W_dec = (const float*)d_in[3];
    const float* b_dec = (const float*)d_in[4];
    float* out = (float*)d_out;

    float*          v   = (float*)d_ws;                          // 768 f32
    unsigned short* APK = (unsigned short*)((char*)d_ws + 4096); // 3 x 65536 bf16 = 384 KB

    pack_M<<<dim3(KK, 3), 256, 0, stream>>>(W_enc, W_dec, b_enc, b_dec, APK, v);
    patch_ae_loop<<<dim3(768), 256, 0, stream>>>(x, APK, v, out);
}

// Round 17
// 41.014 us; speedup vs baseline: 2.6523x; 1.0328x over previous
//
#include <hip/hip_runtime.h>

#define IMG   224
#define IMG2  (IMG*IMG)
#define NN    27          // patches per dim
#define KK    256         // pixels per patch
#define EE    128
#define SCOLS 232         // ring row stride in elems (464 B)
#define RSTR  136         // rec row stride in elems (272 B, b128-aligned)

typedef float f32x4 __attribute__((ext_vector_type(4)));
typedef short s16x8 __attribute__((ext_vector_type(8)));

__device__ __forceinline__ unsigned short f2bf(float f) {
    unsigned int u = __float_as_uint(f);
    u = (u + 0x7fffu + ((u >> 16) & 1u)) >> 16;   // RNE (inputs finite)
    return (unsigned short)u;
}
__device__ __forceinline__ float bf2f(unsigned short u) {
    return __uint_as_float((unsigned int)u << 16);
}
// register-only packed cvt (RNE); single-instruction asm, no early-clobber hazard
__device__ __forceinline__ uint2 pack4(f32x4 r) {
    uint2 u;
    asm("v_cvt_pk_bf16_f32 %0, %1, %2" : "=v"(u.x) : "v"(r.x), "v"(r.y));
    asm("v_cvt_pk_bf16_f32 %0, %1, %2" : "=v"(u.y) : "v"(r.z), "v"(r.w));
    return u;
}

// M[c][k][j] = sum_e W_dec[c][k][e]*W_enc[c][e][j], packed in MFMA A-frag order:
// APK[c][kf(16)][jb(8)][lane(64)][i(8)] = bf16(M[kf*16+(lane&15)][jb*32+8*(lane>>4)+i])
// Also v[c][k] = b_dec[c][k] + sum_e W_dec[c][k][e]*b_enc[c][e].
__global__ void pack_M(const float* __restrict__ W_enc, const float* __restrict__ W_dec,
                       const float* __restrict__ b_enc, const float* __restrict__ b_dec,
                       unsigned short* __restrict__ APK, float* __restrict__ v) {
    int k = blockIdx.x, c = blockIdx.y, j = threadIdx.x;
    const float* wd = W_dec + ((size_t)c*KK + k)*EE;
    const float* we = W_enc + (size_t)c*EE*KK + j;
    float acc = 0.f;
    #pragma unroll 8
    for (int e = 0; e < EE; ++e) acc = fmaf(wd[e], we[(size_t)e*KK], acc);
    int kf = k >> 4, kr = k & 15, jb = j >> 5, g = (j >> 3) & 3, i = j & 7;
    APK[(size_t)c*65536 + (((kf*8 + jb)*64) + g*16 + kr)*8 + i] = f2bf(acc);

    __shared__ float pv[128];
    if (j < EE) pv[j] = wd[j] * b_enc[c*EE + j];
    __syncthreads();
    for (int off = 64; off > 0; off >>= 1) {
        if (j < off) pv[j] += pv[j + off];
        __syncthreads();
    }
    if (j == 0) v[c*KK + k] = pv[0] + b_dec[c*KK + k];
}

// Block = (b, c, quarter q): strips 7q..7q+6 in a loop. 8 waves = 2 prow x 4 kq;
// each wave owns 32 k-rows -> 16 A frags (64 VGPR) asm-pinned once per block.
__global__ __launch_bounds__(512, 4)
void patch_ae_loop(const float* __restrict__ x, const unsigned short* __restrict__ APK,
                   const float* __restrict__ v, float* __restrict__ out) {
    // bijective XCD swizzle: 768 blocks = 8 XCDs x 96
    const int hid = blockIdx.x;
    const int lid = (hid & 7)*96 + (hid >> 3);
    const int q   = lid & 3;
    const int t2  = lid >> 2;       // 0..191
    const int c   = t2 % 3;
    const int b   = t2 / 3;
    const int s0  = 7*q;

    const int tid  = threadIdx.x;
    const int lane = tid & 63, wave = tid >> 6;

    __shared__ __align__(16) unsigned short ring[32*SCOLS];    // 14848 B (4 groups x 8 rows)
    // rec slots: 0 = zero row, 1..27 = patches 0..26, 28 = zero row, 29 = dump (p>=27)
    __shared__ __align__(16) unsigned short rec[2][30][RSTR];  // 16320 B
    __shared__ __align__(16) float vsh[256];                   // 1024 B

    if (tid < 256) vsh[tid] = v[c*256 + tid];
    if (tid < RSTR) {   // zero rows (slots 0 and 28, both prows)
        rec[0][0][tid] = 0; rec[0][28][tid] = 0;
        rec[1][0][tid] = 0; rec[1][28][tid] = 0;
    }

    // wave constants: 8 waves = 2 prow x 4 kq (32 k-rows each)
    const int prow   = wave >> 2;      // 0: ny=s, 1: ny=s-1
    const int kq     = wave & 3;
    const int kfbase = prow*8 + kq*2;
    const int g = lane >> 4, lr = lane & 15;
    const int jx0 = (g & 1)*8;
    const int c1 = (lr <= 10) ? (128 + 8*lr) : 208;   // pf1 col, clamped (p>=27 unused)
    const int rowoff = prow ? -8 : 0;

    // ---- A: 16 frags loaded ONCE, asm-pinned (13-bit signed imm: offsets < 4096) ----
    const int kfu = __builtin_amdgcn_readfirstlane(kfbase);
    const char* abase = (const char*)(APK + (size_t)c*65536) + (size_t)kfu*8192;
    const int v0a = lane*16,       v0b = v0a + 4096;
    const int v1a = v0a + 8192,    v1b = v0a + 12288;

#define ALD(VAR, VOFF, OFFSTR)                                      \
    asm volatile("global_load_dwordx4 %0, %1, %2 offset:" OFFSTR    \
                 : "=v"(VAR) : "v"(VOFF), "s"(abase));

    s16x8 a0_0,a0_1,a0_2,a0_3,a0_4,a0_5,a0_6,a0_7;
    s16x8 a1_0,a1_1,a1_2,a1_3,a1_4,a1_5,a1_6,a1_7;
    ALD(a0_0, v0a, "0")  ALD(a0_1, v0a, "1024") ALD(a0_2, v0a, "2048") ALD(a0_3, v0a, "3072")
    ALD(a0_4, v0b, "0")  ALD(a0_5, v0b, "1024") ALD(a0_6, v0b, "2048") ALD(a0_7, v0b, "3072")
    ALD(a1_0, v1a, "0")  ALD(a1_1, v1a, "1024") ALD(a1_2, v1a, "2048") ALD(a1_3, v1a, "3072")
    ALD(a1_4, v1b, "0")  ALD(a1_5, v1b, "1024") ALD(a1_6, v1b, "2048") ALD(a1_7, v1b, "3072")
#undef ALD

    const float* xb = x + (size_t)(b*3 + c)*IMG2;

    // ---- prologue staging: groups s0-1, s0, s0+1 (24 rows, row-clamped) ----
    #pragma unroll
    for (int it = 0; it < 2; ++it) {
        int ci = tid + it*512;
        if (ci < 672) {
            int r  = ci / 28, cc = ci - (ci/28)*28;
            int ar = 8*s0 - 8 + r;                 // absolute image row (may be OOB)
            int yr = ar < 0 ? 0 : (ar > 223 ? 223 : ar);
            const float4* src = (const float4*)(xb + (size_t)yr*IMG + cc*8);
            float4 lo = src[0], hi = src[1];
            uint2 u0 = pack4((f32x4){lo.x, lo.y, lo.z, lo.w});
            uint2 u1 = pack4((f32x4){hi.x, hi.y, hi.z, hi.w});
            *((uint4*)&ring[(ar & 31)*SCOLS + cc*8]) = make_uint4(u0.x, u0.y, u1.x, u1.y);
        }
    }
    __syncthreads();
    asm volatile("s_waitcnt vmcnt(0)");     // A frags resident before first MFMA
    __builtin_amdgcn_sched_barrier(0);

    // per-thread staging constants (tid<224: one 8-px chunk per row-group)
    const int rr  = tid / 28;
    const int cc2 = tid - 28*(tid/28);

    // epilogue constants
    const int eq  = tid % 28, ery = tid / 28;       // col group, row (tid<224)
    const int ev1 = (eq < 27), ev0 = (eq > 0);
    const int ero = ery*16;

#define MFMA2(AF, B0, B1, F)                                                             \
        acc[F][0] = __builtin_amdgcn_mfma_f32_16x16x32_bf16(AF, B0, acc[F][0], 0, 0, 0); \
        acc[F][1] = __builtin_amdgcn_mfma_f32_16x16x32_bf16(AF, B1, acc[F][1], 0, 0, 0);

#define MSTEP(JB, A0, A1)                                                            \
        {                                                                            \
            const int jy = 2*(JB) + (g >> 1);                                        \
            const unsigned short* srow = &ring[((rowb + jy) & 31)*SCOLS + jx0];      \
            s16x8 bf0 = *((const s16x8*)&srow[8*lr]);                                \
            s16x8 bf1 = *((const s16x8*)&srow[c1]);                                  \
            __builtin_amdgcn_s_setprio(1);                                           \
            MFMA2(A0, bf0, bf1, 0) MFMA2(A1, bf0, bf1, 1)                            \
            __builtin_amdgcn_s_setprio(0);                                           \
        }

    #pragma unroll 1
    for (int s = s0; s < s0 + 7; ++s) {
        // 1. issue prefetch of group s+2 (8 rows; lands in regs, hides under MFMA)
        f32x4 ga0, ga1;
        if (tid < 224) {
            int yr = 8*(s+2) + rr; if (yr > 223) yr = 223;   // clamp: garbage rows unread
            int voffx = yr*(IMG*4) + cc2*32;
            asm volatile("global_load_dwordx4 %0, %1, %2"           : "=v"(ga0) : "v"(voffx), "s"(xb));
            asm volatile("global_load_dwordx4 %0, %1, %2 offset:16" : "=v"(ga1) : "v"(voffx), "s"(xb));
        }

        // 2. MFMA over strip s (A pinned in regs, B from ring)
        f32x4 acc[2][2];
        #pragma unroll
        for (int f = 0; f < 2; ++f)
            #pragma unroll
            for (int pf = 0; pf < 2; ++pf)
                acc[f][pf] = (f32x4){0.f, 0.f, 0.f, 0.f};
        const int rowb = 8*s + rowoff;
        MSTEP(0, a0_0, a1_0)
        MSTEP(1, a0_1, a1_1)
        MSTEP(2, a0_2, a1_2)
        MSTEP(3, a0_3, a1_3)
        MSTEP(4, a0_4, a1_4)
        MSTEP(5, a0_5, a1_5)
        MSTEP(6, a0_6, a1_6)
        MSTEP(7, a0_7, a1_7)

        // 3. bias + bf16 rec store: patch p -> slot p+1 (p>=27 -> dump slot 29)
        #pragma unroll
        for (int f = 0; f < 2; ++f) {
            int klocal = kq*32 + f*16 + g*4;
            f32x4 bias = *((const f32x4*)&vsh[prow*128 + klocal]);
            #pragma unroll
            for (int pf = 0; pf < 2; ++pf) {
                f32x4 r = acc[f][pf] + bias;
                int pidx = pf*16 + lr + 1;
                if (pidx >= 28) pidx = 29;
                *((uint2*)&rec[prow][pidx][klocal]) = pack4(r);
            }
        }
        __syncthreads();   // 4. rec ready; ring reads of strip s done

        // 5. write prefetched group s+2 into ring (slot disjoint from groups s..s+2 reads)
        if (tid < 224) {
            asm volatile("s_waitcnt vmcnt(0)");
            __builtin_amdgcn_sched_barrier(0);
            uint2 u0 = pack4(ga0);
            uint2 u1 = pack4(ga1);
            int ar2 = 8*(s+2) + rr;
            *((uint4*)&ring[(ar2 & 31)*SCOLS + cc2*8]) = make_uint4(u0.x, u0.y, u1.x, u1.y);
        }

        // 6. epilogue for strip s: 4 b128 rec reads, 2 dwordx4 stores per thread
        if (tid < 224) {
            const int h0 = (s < 27);
            const int h1 = (s > 0);
            const int shift = (ev0 & ev1) + (h0 & h1);
            const float inv = __int_as_float(0x3f800000 - (shift << 23)); // exact 1/2^shift
            float sum[8];
            #pragma unroll
            for (int d = 0; d < 8; ++d) sum[d] = 0.f;
            if (h0) {
                s16x8 rrv = *((const s16x8*)&rec[0][eq+1][ero]);
                s16x8 llv = *((const s16x8*)&rec[0][eq][ero + 8]);
                #pragma unroll
                for (int d = 0; d < 8; ++d)
                    sum[d] += bf2f((unsigned short)rrv[d]) + bf2f((unsigned short)llv[d]);
            }
            if (h1) {
                s16x8 rrv = *((const s16x8*)&rec[1][eq+1][ero]);
                s16x8 llv = *((const s16x8*)&rec[1][eq][ero + 8]);
                #pragma unroll
                for (int d = 0; d < 8; ++d)
                    sum[d] += bf2f((unsigned short)rrv[d]) + bf2f((unsigned short)llv[d]);
            }
            float* orow = out + (size_t)(b*3 + c)*IMG2 + (size_t)(8*s + ery)*IMG + 8*eq;
            f32x4 o0 = {sum[0]*inv, sum[1]*inv, sum[2]*inv, sum[3]*inv};
            f32x4 o1 = {sum[4]*inv, sum[5]*inv, sum[6]*inv, sum[7]*inv};
            *((f32x4*)orow)       = o0;
            *((f32x4*)(orow + 4)) = o1;
        }
        __syncthreads();   // 7. rec reads done + ring writes visible before next iter
    }
#undef MSTEP
#undef MFMA2
}

extern "C" void kernel_launch(void* const* d_in, const int* in_sizes, int n_in,
                              void* d_out, int out_size, void* d_ws, size_t ws_size,
                              hipStream_t stream) {
    (void)in_sizes; (void)n_in; (void)out_size; (void)ws_size;
    const float* x     = (const float*)d_in[0];
    const float* W_enc = (const float*)d_in[1];
    const float* b_enc = (const float*)d_in[2];
    const float* W_dec = (const float*)d_in[3];
    const float* b_dec = (const float*)d_in[4];
    float* out = (float*)d_out;

    float*          v   = (float*)d_ws;                          // 768 f32
    unsigned short* APK = (unsigned short*)((char*)d_ws + 4096); // 3 x 65536 bf16 = 384 KB

    pack_M<<<dim3(KK, 3), 256, 0, stream>>>(W_enc, W_dec, b_enc, b_dec, APK, v);
    patch_ae_loop<<<dim3(768), 512, 0, stream>>>(x, APK, v, out);
}

// Round 18
// 40.419 us; speedup vs baseline: 2.6914x; 1.0147x over previous
//
#include <hip/hip_runtime.h>

#define IMG   224
#define IMG2  (IMG*IMG)
#define NN    27          // patches per dim
#define KK    256         // pixels per patch
#define EE    128
#define SCOLS 232         // ring row stride in elems (464 B)
#define RSTR  136         // rec row stride in elems (272 B, b128-aligned)

typedef float f32x4 __attribute__((ext_vector_type(4)));
typedef short s16x8 __attribute__((ext_vector_type(8)));
typedef short s16x4 __attribute__((ext_vector_type(4)));

__device__ __forceinline__ unsigned short f2bf(float f) {
    unsigned int u = __float_as_uint(f);
    u = (u + 0x7fffu + ((u >> 16) & 1u)) >> 16;   // RNE (inputs finite)
    return (unsigned short)u;
}
__device__ __forceinline__ float bf2f(unsigned short u) {
    return __uint_as_float((unsigned int)u << 16);
}
// register-only packed cvt (RNE); single-instruction asm, no early-clobber hazard
__device__ __forceinline__ uint2 pack4(f32x4 r) {
    uint2 u;
    asm("v_cvt_pk_bf16_f32 %0, %1, %2" : "=v"(u.x) : "v"(r.x), "v"(r.y));
    asm("v_cvt_pk_bf16_f32 %0, %1, %2" : "=v"(u.y) : "v"(r.z), "v"(r.w));
    return u;
}

// KPB=2: each block computes 2 k-rows per full W_enc stream (halves L2 traffic).
// M[c][k][j] = sum_e W_dec[c][k][e]*W_enc[c][e][j], packed in MFMA A-frag order;
// v[c][k] = b_dec[c][k] + sum_e W_dec[c][k][e]*b_enc[c][e] (fused dual reduction).
__global__ void pack_M(const float* __restrict__ W_enc, const float* __restrict__ W_dec,
                       const float* __restrict__ b_enc, const float* __restrict__ b_dec,
                       unsigned short* __restrict__ APK, float* __restrict__ v) {
    const int k0 = blockIdx.x*2, c = blockIdx.y, j = threadIdx.x;
    const float* wd0 = W_dec + ((size_t)c*KK + k0)*EE;
    const float* wd1 = wd0 + EE;
    const float* we  = W_enc + (size_t)c*EE*KK + j;
    float a0 = 0.f, a1 = 0.f;
    #pragma unroll 8
    for (int e = 0; e < EE; ++e) {
        float wv = we[(size_t)e*KK];
        a0 = fmaf(wd0[e], wv, a0);
        a1 = fmaf(wd1[e], wv, a1);
    }
    const int jb = j >> 5, g = (j >> 3) & 3, i = j & 7;
    {
        int kf = k0 >> 4, kr = k0 & 15;
        APK[(size_t)c*65536 + (((kf*8 + jb)*64) + g*16 + kr)*8 + i] = f2bf(a0);
        kf = (k0+1) >> 4; kr = (k0+1) & 15;
        APK[(size_t)c*65536 + (((kf*8 + jb)*64) + g*16 + kr)*8 + i] = f2bf(a1);
    }

    __shared__ float pv[256];
    const float* be = b_enc + c*EE;
    pv[j] = (j < EE) ? wd0[j]*be[j] : wd1[j-EE]*be[j-EE];
    __syncthreads();
    for (int off = 64; off > 0; off >>= 1) {
        if ((j & 127) < off) pv[j] += pv[j + off];
        __syncthreads();
    }
    if (j == 0)   v[c*KK + k0]     = pv[0]   + b_dec[c*KK + k0];
    if (j == 128) v[c*KK + k0 + 1] = pv[128] + b_dec[c*KK + k0 + 1];
}

// Block = (b, c, quarter q): strips 7q..7q+6 in a loop. 8 waves = 2 prow x 4 kq;
// each wave owns 32 k-rows -> 16 A frags (64 VGPR) asm-pinned once per block.
__global__ __launch_bounds__(512, 4)
void patch_ae_loop(const float* __restrict__ x, const unsigned short* __restrict__ APK,
                   const float* __restrict__ v, float* __restrict__ out) {
    // bijective XCD swizzle: 768 blocks = 8 XCDs x 96
    const int hid = blockIdx.x;
    const int lid = (hid & 7)*96 + (hid >> 3);
    const int q   = lid & 3;
    const int t2  = lid >> 2;       // 0..191
    const int c   = t2 % 3;
    const int b   = t2 / 3;
    const int s0  = 7*q;

    const int tid  = threadIdx.x;
    const int lane = tid & 63, wave = tid >> 6;

    __shared__ __align__(16) unsigned short ring[32*SCOLS];    // 14848 B (4 groups x 8 rows)
    // rec slots: 0 = zero row, 1..27 = patches 0..26, 28 = zero row, 29 = dump (p>=27)
    __shared__ __align__(16) unsigned short rec[2][30][RSTR];  // 16320 B
    __shared__ __align__(16) float vsh[256];                   // 1024 B

    if (tid < 256) vsh[tid] = v[c*256 + tid];
    if (tid < RSTR) {   // zero rows (slots 0 and 28, both prows)
        rec[0][0][tid] = 0; rec[0][28][tid] = 0;
        rec[1][0][tid] = 0; rec[1][28][tid] = 0;
    }

    // wave constants: 8 waves = 2 prow x 4 kq (32 k-rows each)
    const int prow   = wave >> 2;      // 0: ny=s, 1: ny=s-1
    const int kq     = wave & 3;
    const int kfbase = prow*8 + kq*2;
    const int g = lane >> 4, lr = lane & 15;
    const int jx0 = (g & 1)*8;
    const int c1 = (lr <= 10) ? (128 + 8*lr) : 208;   // pf1 col, clamped (p>=27 unused)
    const int rowoff = prow ? -8 : 0;

    // ---- A: 16 frags loaded ONCE, asm-pinned (13-bit signed imm: offsets < 4096) ----
    const int kfu = __builtin_amdgcn_readfirstlane(kfbase);
    const char* abase = (const char*)(APK + (size_t)c*65536) + (size_t)kfu*8192;
    const int v0a = lane*16,       v0b = v0a + 4096;
    const int v1a = v0a + 8192,    v1b = v0a + 12288;

#define ALD(VAR, VOFF, OFFSTR)                                      \
    asm volatile("global_load_dwordx4 %0, %1, %2 offset:" OFFSTR    \
                 : "=v"(VAR) : "v"(VOFF), "s"(abase));

    s16x8 a0_0,a0_1,a0_2,a0_3,a0_4,a0_5,a0_6,a0_7;
    s16x8 a1_0,a1_1,a1_2,a1_3,a1_4,a1_5,a1_6,a1_7;
    ALD(a0_0, v0a, "0")  ALD(a0_1, v0a, "1024") ALD(a0_2, v0a, "2048") ALD(a0_3, v0a, "3072")
    ALD(a0_4, v0b, "0")  ALD(a0_5, v0b, "1024") ALD(a0_6, v0b, "2048") ALD(a0_7, v0b, "3072")
    ALD(a1_0, v1a, "0")  ALD(a1_1, v1a, "1024") ALD(a1_2, v1a, "2048") ALD(a1_3, v1a, "3072")
    ALD(a1_4, v1b, "0")  ALD(a1_5, v1b, "1024") ALD(a1_6, v1b, "2048") ALD(a1_7, v1b, "3072")
#undef ALD

    const float* xb = x + (size_t)(b*3 + c)*IMG2;

    // ---- prologue staging: groups s0-1, s0, s0+1 (24 rows, row-clamped) ----
    #pragma unroll
    for (int it = 0; it < 2; ++it) {
        int ci = tid + it*512;
        if (ci < 672) {
            int r  = ci / 28, cc = ci - (ci/28)*28;
            int ar = 8*s0 - 8 + r;                 // absolute image row (may be OOB)
            int yr = ar < 0 ? 0 : (ar > 223 ? 223 : ar);
            const float4* src = (const float4*)(xb + (size_t)yr*IMG + cc*8);
            float4 lo = src[0], hi = src[1];
            uint2 u0 = pack4((f32x4){lo.x, lo.y, lo.z, lo.w});
            uint2 u1 = pack4((f32x4){hi.x, hi.y, hi.z, hi.w});
            *((uint4*)&ring[(ar & 31)*SCOLS + cc*8]) = make_uint4(u0.x, u0.y, u1.x, u1.y);
        }
    }
    __syncthreads();
    asm volatile("s_waitcnt vmcnt(0)");     // A frags resident before first MFMA
    __builtin_amdgcn_sched_barrier(0);

    // per-strip staging constants (tid<448: one 4-px chunk of the 8-row group)
    const int sr  = tid / 56;           // row in group 0..7
    const int sc4 = tid - 56*(tid/56);  // 4-px chunk 0..55

    // epilogue constants (tid<448: 4 output px)
    const int em   = tid % 56, ery = tid / 56;    // 4-col group, row
    const int eq   = em >> 1, ehh = em & 1;       // 8-col group, half
    const int ev1  = (eq < 27), ev0 = (eq > 0);
    const int kl1  = ery*16 + 4*ehh;              // right-patch rec offset
    const int kl0  = kl1 + 8;                     // left-patch rec offset

#define MFMA2(AF, B0, B1, F)                                                             \
        acc[F][0] = __builtin_amdgcn_mfma_f32_16x16x32_bf16(AF, B0, acc[F][0], 0, 0, 0); \
        acc[F][1] = __builtin_amdgcn_mfma_f32_16x16x32_bf16(AF, B1, acc[F][1], 0, 0, 0);

#define MSTEP(JB, A0, A1)                                                            \
        {                                                                            \
            const int jy = 2*(JB) + (g >> 1);                                        \
            const unsigned short* srow = &ring[((rowb + jy) & 31)*SCOLS + jx0];      \
            s16x8 bf0 = *((const s16x8*)&srow[8*lr]);                                \
            s16x8 bf1 = *((const s16x8*)&srow[c1]);                                  \
            __builtin_amdgcn_s_setprio(1);                                           \
            MFMA2(A0, bf0, bf1, 0) MFMA2(A1, bf0, bf1, 1)                            \
            __builtin_amdgcn_s_setprio(0);                                           \
        }

    #pragma unroll 1
    for (int s = s0; s < s0 + 7; ++s) {
        // 1. issue prefetch of group s+2 (8 rows; 448 threads x 16B)
        f32x4 ga0;
        if (tid < 448) {
            int yr = 8*(s+2) + sr; if (yr > 223) yr = 223;   // clamp: garbage rows unread
            int voffx = yr*(IMG*4) + sc4*16;
            asm volatile("global_load_dwordx4 %0, %1, %2" : "=v"(ga0) : "v"(voffx), "s"(xb));
        }

        // 2. MFMA over strip s (A pinned in regs, B from ring)
        f32x4 acc[2][2];
        #pragma unroll
        for (int f = 0; f < 2; ++f)
            #pragma unroll
            for (int pf = 0; pf < 2; ++pf)
                acc[f][pf] = (f32x4){0.f, 0.f, 0.f, 0.f};
        const int rowb = 8*s + rowoff;
        MSTEP(0, a0_0, a1_0)
        MSTEP(1, a0_1, a1_1)
        MSTEP(2, a0_2, a1_2)
        MSTEP(3, a0_3, a1_3)
        MSTEP(4, a0_4, a1_4)
        MSTEP(5, a0_5, a1_5)
        MSTEP(6, a0_6, a1_6)
        MSTEP(7, a0_7, a1_7)

        // 3. bias + bf16 rec store: patch p -> slot p+1 (p>=27 -> dump slot 29)
        #pragma unroll
        for (int f = 0; f < 2; ++f) {
            int klocal = kq*32 + f*16 + g*4;
            f32x4 bias = *((const f32x4*)&vsh[prow*128 + klocal]);
            #pragma unroll
            for (int pf = 0; pf < 2; ++pf) {
                f32x4 r = acc[f][pf] + bias;
                int pidx = pf*16 + lr + 1;
                if (pidx >= 28) pidx = 29;
                *((uint2*)&rec[prow][pidx][klocal]) = pack4(r);
            }
        }
        __syncthreads();   // 4. rec ready; ring reads of strip s done

        // 5. epilogue for strip s: 448 threads, 4 px each (4 b64 reads, 1 store)
        if (tid < 448) {
            const int h0 = (s < 27);
            const int h1 = (s > 0);
            const int shift = (ev0 & ev1) + (h0 & h1);
            const float inv = __int_as_float(0x3f800000 - (shift << 23)); // exact 1/2^shift
            float sum[4];
            #pragma unroll
            for (int d = 0; d < 4; ++d) sum[d] = 0.f;
            if (h0) {
                s16x4 rrv = *((const s16x4*)&rec[0][eq+1][kl1]);   // right: patch eq
                s16x4 llv = *((const s16x4*)&rec[0][eq][kl0]);     // left: patch eq-1
                #pragma unroll
                for (int d = 0; d < 4; ++d)
                    sum[d] += bf2f((unsigned short)rrv[d]) + bf2f((unsigned short)llv[d]);
            }
            if (h1) {
                s16x4 rrv = *((const s16x4*)&rec[1][eq+1][kl1]);
                s16x4 llv = *((const s16x4*)&rec[1][eq][kl0]);
                #pragma unroll
                for (int d = 0; d < 4; ++d)
                    sum[d] += bf2f((unsigned short)rrv[d]) + bf2f((unsigned short)llv[d]);
            }
            float* orow = out + (size_t)(b*3 + c)*IMG2 + (size_t)(8*s + ery)*IMG + 4*em;
            f32x4 o = {sum[0]*inv, sum[1]*inv, sum[2]*inv, sum[3]*inv};
            *((f32x4*)orow) = o;
        }

        // 6. write prefetched group s+2 into ring (slot disjoint from groups s..s+2 reads)
        if (tid < 448) {
            asm volatile("s_waitcnt vmcnt(0)");
            __builtin_amdgcn_sched_barrier(0);
            uint2 u0 = pack4(ga0);
            int ar2 = 8*(s+2) + sr;
            *((uint2*)&ring[(ar2 & 31)*SCOLS + sc4*4]) = u0;
        }
        __syncthreads();   // 7. rec reads done + ring writes visible before next iter
    }
#undef MSTEP
#undef MFMA2
}

extern "C" void kernel_launch(void* const* d_in, const int* in_sizes, int n_in,
                              void* d_out, int out_size, void* d_ws, size_t ws_size,
                              hipStream_t stream) {
    (void)in_sizes; (void)n_in; (void)out_size; (void)ws_size;
    const float* x     = (const float*)d_in[0];
    const float* W_enc = (const float*)d_in[1];
    const float* b_enc = (const float*)d_in[2];
    const float* W_dec = (const float*)d_in[3];
    const float* b_dec = (const float*)d_in[4];
    float* out = (float*)d_out;

    float*          v   = (float*)d_ws;                          // 768 f32
    unsigned short* APK = (unsigned short*)((char*)d_ws + 4096); // 3 x 65536 bf16 = 384 KB

    pack_M<<<dim3(KK/2, 3), 256, 0, stream>>>(W_enc, W_dec, b_enc, b_dec, APK, v);
    patch_ae_loop<<<dim3(768), 512, 0, stream>>>(x, APK, v, out);
}

// Round 19
// 40.369 us; speedup vs baseline: 2.6947x; 1.0012x over previous
//
#include <hip/hip_runtime.h>

#define IMG   224
#define IMG2  (IMG*IMG)
#define NN    27          // patches per dim
#define KK    256         // pixels per patch
#define EE    128
#define SCOLS 232         // ring row stride in elems (464 B)
#define RSTR  136         // rec row stride in elems (272 B, b128-aligned)

typedef float f32x4 __attribute__((ext_vector_type(4)));
typedef short s16x8 __attribute__((ext_vector_type(8)));
typedef short s16x4 __attribute__((ext_vector_type(4)));

__device__ __forceinline__ unsigned short f2bf(float f) {
    unsigned int u = __float_as_uint(f);
    u = (u + 0x7fffu + ((u >> 16) & 1u)) >> 16;   // RNE (inputs finite)
    return (unsigned short)u;
}
__device__ __forceinline__ float bf2f(unsigned short u) {
    return __uint_as_float((unsigned int)u << 16);
}
// register-only packed cvt (RNE); single-instruction asm, no early-clobber hazard
__device__ __forceinline__ uint2 pack4(f32x4 r) {
    uint2 u;
    asm("v_cvt_pk_bf16_f32 %0, %1, %2" : "=v"(u.x) : "v"(r.x), "v"(r.y));
    asm("v_cvt_pk_bf16_f32 %0, %1, %2" : "=v"(u.y) : "v"(r.z), "v"(r.w));
    return u;
}

// KPB=2: each block computes 2 k-rows per full W_enc stream (halves L2 traffic).
__global__ void pack_M(const float* __restrict__ W_enc, const float* __restrict__ W_dec,
                       const float* __restrict__ b_enc, const float* __restrict__ b_dec,
                       unsigned short* __restrict__ APK, float* __restrict__ v) {
    const int k0 = blockIdx.x*2, c = blockIdx.y, j = threadIdx.x;
    const float* wd0 = W_dec + ((size_t)c*KK + k0)*EE;
    const float* wd1 = wd0 + EE;
    const float* we  = W_enc + (size_t)c*EE*KK + j;
    float a0 = 0.f, a1 = 0.f;
    #pragma unroll 8
    for (int e = 0; e < EE; ++e) {
        float wv = we[(size_t)e*KK];
        a0 = fmaf(wd0[e], wv, a0);
        a1 = fmaf(wd1[e], wv, a1);
    }
    const int jb = j >> 5, g = (j >> 3) & 3, i = j & 7;
    {
        int kf = k0 >> 4, kr = k0 & 15;
        APK[(size_t)c*65536 + (((kf*8 + jb)*64) + g*16 + kr)*8 + i] = f2bf(a0);
        kf = (k0+1) >> 4; kr = (k0+1) & 15;
        APK[(size_t)c*65536 + (((kf*8 + jb)*64) + g*16 + kr)*8 + i] = f2bf(a1);
    }

    __shared__ float pv[256];
    const float* be = b_enc + c*EE;
    pv[j] = (j < EE) ? wd0[j]*be[j] : wd1[j-EE]*be[j-EE];
    __syncthreads();
    for (int off = 64; off > 0; off >>= 1) {
        if ((j & 127) < off) pv[j] += pv[j + off];
        __syncthreads();
    }
    if (j == 0)   v[c*KK + k0]     = pv[0]   + b_dec[c*KK + k0];
    if (j == 128) v[c*KK + k0 + 1] = pv[128] + b_dec[c*KK + k0 + 1];
}

// Block = (b, c, quarter q): strips 7q..7q+6 in a loop. 8 waves = 2 prow x 4 kq;
// 16 A frags (64 VGPR) asm-pinned once per block. Single barrier per iteration:
// rec double-buffered by strip parity; epilogue for strip s-1 runs inside iter s.
__global__ __launch_bounds__(512, 4)
void patch_ae_loop(const float* __restrict__ x, const unsigned short* __restrict__ APK,
                   const float* __restrict__ v, float* __restrict__ out) {
    // bijective XCD swizzle: 768 blocks = 8 XCDs x 96
    const int hid = blockIdx.x;
    const int lid = (hid & 7)*96 + (hid >> 3);
    const int q   = lid & 3;
    const int t2  = lid >> 2;       // 0..191
    const int c   = t2 % 3;
    const int b   = t2 / 3;
    const int s0  = 7*q;

    const int tid  = threadIdx.x;
    const int lane = tid & 63, wave = tid >> 6;

    __shared__ __align__(16) unsigned short ring[32*SCOLS];       // 14848 B (4 groups x 8 rows)
    // rec[parity][prow]: slots 0=zero, 1..27=patches 0..26, 28=zero, 29=dump
    __shared__ __align__(16) unsigned short rec[2][2][30][RSTR];  // 32640 B
    __shared__ __align__(16) float vsh[256];                      // 1024 B

    if (tid < 256) vsh[tid] = v[c*256 + tid];
    if (tid < RSTR) {   // zero rows (slots 0 and 28, both parities, both prows)
        rec[0][0][0][tid] = 0; rec[0][0][28][tid] = 0;
        rec[0][1][0][tid] = 0; rec[0][1][28][tid] = 0;
        rec[1][0][0][tid] = 0; rec[1][0][28][tid] = 0;
        rec[1][1][0][tid] = 0; rec[1][1][28][tid] = 0;
    }

    // wave constants: 8 waves = 2 prow x 4 kq (32 k-rows each)
    const int prow   = wave >> 2;      // 0: ny=s, 1: ny=s-1
    const int kq     = wave & 3;
    const int kfbase = prow*8 + kq*2;
    const int g = lane >> 4, lr = lane & 15;
    const int jx0 = (g & 1)*8;
    const int c1 = (lr <= 10) ? (128 + 8*lr) : 208;   // pf1 col, clamped (p>=27 unused)
    const int rowoff = prow ? -8 : 0;

    // ---- A: 16 frags loaded ONCE, asm-pinned (13-bit signed imm: offsets < 4096) ----
    const int kfu = __builtin_amdgcn_readfirstlane(kfbase);
    const char* abase = (const char*)(APK + (size_t)c*65536) + (size_t)kfu*8192;
    const int v0a = lane*16,       v0b = v0a + 4096;
    const int v1a = v0a + 8192,    v1b = v0a + 12288;

#define ALD(VAR, VOFF, OFFSTR)                                      \
    asm volatile("global_load_dwordx4 %0, %1, %2 offset:" OFFSTR    \
                 : "=v"(VAR) : "v"(VOFF), "s"(abase));

    s16x8 a0_0,a0_1,a0_2,a0_3,a0_4,a0_5,a0_6,a0_7;
    s16x8 a1_0,a1_1,a1_2,a1_3,a1_4,a1_5,a1_6,a1_7;
    ALD(a0_0, v0a, "0")  ALD(a0_1, v0a, "1024") ALD(a0_2, v0a, "2048") ALD(a0_3, v0a, "3072")
    ALD(a0_4, v0b, "0")  ALD(a0_5, v0b, "1024") ALD(a0_6, v0b, "2048") ALD(a0_7, v0b, "3072")
    ALD(a1_0, v1a, "0")  ALD(a1_1, v1a, "1024") ALD(a1_2, v1a, "2048") ALD(a1_3, v1a, "3072")
    ALD(a1_4, v1b, "0")  ALD(a1_5, v1b, "1024") ALD(a1_6, v1b, "2048") ALD(a1_7, v1b, "3072")
#undef ALD

    const float* xb = x + (size_t)(b*3 + c)*IMG2;

    // ---- prologue staging: groups s0-1, s0, s0+1 (24 rows, row-clamped) ----
    #pragma unroll
    for (int it = 0; it < 2; ++it) {
        int ci = tid + it*512;
        if (ci < 672) {
            int r  = ci / 28, cc = ci - (ci/28)*28;
            int ar = 8*s0 - 8 + r;                 // absolute image row (may be OOB)
            int yr = ar < 0 ? 0 : (ar > 223 ? 223 : ar);
            const float4* src = (const float4*)(xb + (size_t)yr*IMG + cc*8);
            float4 lo = src[0], hi = src[1];
            uint2 u0 = pack4((f32x4){lo.x, lo.y, lo.z, lo.w});
            uint2 u1 = pack4((f32x4){hi.x, hi.y, hi.z, hi.w});
            *((uint4*)&ring[(ar & 31)*SCOLS + cc*8]) = make_uint4(u0.x, u0.y, u1.x, u1.y);
        }
    }
    __syncthreads();
    asm volatile("s_waitcnt vmcnt(0)");     // A frags resident before first MFMA
    __builtin_amdgcn_sched_barrier(0);

    // per-strip staging constants (tid<448: one 4-px chunk of the 8-row group)
    const int sr  = tid / 56;
    const int sc4 = tid - 56*(tid/56);

    // epilogue constants (tid<448: 4 output px)
    const int em   = tid % 56, ery = tid / 56;
    const int eq   = em >> 1, ehh = em & 1;
    const int ev1  = (eq < 27), ev0 = (eq > 0);
    const int kl1  = ery*16 + 4*ehh;
    const int kl0  = kl1 + 8;

#define EPILOGUE(ES)                                                                     \
        if (tid < 448) {                                                                 \
            const int par = (ES) & 1;                                                    \
            const int h0 = ((ES) < 27);                                                  \
            const int h1 = ((ES) > 0);                                                   \
            const int shift = (ev0 & ev1) + (h0 & h1);                                   \
            const float inv = __int_as_float(0x3f800000 - (shift << 23));                \
            float sum[4];                                                                \
            _Pragma("unroll")                                                            \
            for (int d = 0; d < 4; ++d) sum[d] = 0.f;                                    \
            if (h0) {                                                                    \
                s16x4 rrv = *((const s16x4*)&rec[par][0][eq+1][kl1]);                    \
                s16x4 llv = *((const s16x4*)&rec[par][0][eq][kl0]);                      \
                _Pragma("unroll")                                                        \
                for (int d = 0; d < 4; ++d)                                              \
                    sum[d] += bf2f((unsigned short)rrv[d]) + bf2f((unsigned short)llv[d]); \
            }                                                                            \
            if (h1) {                                                                    \
                s16x4 rrv = *((const s16x4*)&rec[par][1][eq+1][kl1]);                    \
                s16x4 llv = *((const s16x4*)&rec[par][1][eq][kl0]);                      \
                _Pragma("unroll")                                                        \
                for (int d = 0; d < 4; ++d)                                              \
                    sum[d] += bf2f((unsigned short)rrv[d]) + bf2f((unsigned short)llv[d]); \
            }                                                                            \
            float* orow = out + (size_t)(b*3 + c)*IMG2 + (size_t)(8*(ES) + ery)*IMG + 4*em; \
            f32x4 o = {sum[0]*inv, sum[1]*inv, sum[2]*inv, sum[3]*inv};                  \
            *((f32x4*)orow) = o;                                                         \
        }

#define MFMA2(AF, B0, B1, F)                                                             \
        acc[F][0] = __builtin_amdgcn_mfma_f32_16x16x32_bf16(AF, B0, acc[F][0], 0, 0, 0); \
        acc[F][1] = __builtin_amdgcn_mfma_f32_16x16x32_bf16(AF, B1, acc[F][1], 0, 0, 0);

#define MSTEP(JB, A0, A1)                                                            \
        {                                                                            \
            const int jy = 2*(JB) + (g >> 1);                                        \
            const unsigned short* srow = &ring[((rowb + jy) & 31)*SCOLS + jx0];      \
            s16x8 bf0 = *((const s16x8*)&srow[8*lr]);                                \
            s16x8 bf1 = *((const s16x8*)&srow[c1]);                                  \
            __builtin_amdgcn_s_setprio(1);                                           \
            MFMA2(A0, bf0, bf1, 0) MFMA2(A1, bf0, bf1, 1)                            \
            __builtin_amdgcn_s_setprio(0);                                           \
        }

    #pragma unroll 1
    for (int s = s0; s < s0 + 7; ++s) {
        // 1. issue prefetch of group s+2 (8 rows; 448 threads x 16B)
        f32x4 ga0;
        if (tid < 448) {
            int yr = 8*(s+2) + sr; if (yr > 223) yr = 223;   // clamp: garbage rows unread
            int voffx = yr*(IMG*4) + sc4*16;
            asm volatile("global_load_dwordx4 %0, %1, %2" : "=v"(ga0) : "v"(voffx), "s"(xb));
        }

        // 2. MFMA over strip s (A pinned in regs, B from ring)
        f32x4 acc[2][2];
        #pragma unroll
        for (int f = 0; f < 2; ++f)
            #pragma unroll
            for (int pf = 0; pf < 2; ++pf)
                acc[f][pf] = (f32x4){0.f, 0.f, 0.f, 0.f};
        const int rowb = 8*s + rowoff;
        MSTEP(0, a0_0, a1_0)
        MSTEP(1, a0_1, a1_1)
        MSTEP(2, a0_2, a1_2)
        MSTEP(3, a0_3, a1_3)
        MSTEP(4, a0_4, a1_4)
        MSTEP(5, a0_5, a1_5)
        MSTEP(6, a0_6, a1_6)
        MSTEP(7, a0_7, a1_7)

        // 3. bias + bf16 rec store into parity buffer s&1
        {
            const int par = s & 1;
            #pragma unroll
            for (int f = 0; f < 2; ++f) {
                int klocal = kq*32 + f*16 + g*4;
                f32x4 bias = *((const f32x4*)&vsh[prow*128 + klocal]);
                #pragma unroll
                for (int pf = 0; pf < 2; ++pf) {
                    f32x4 r = acc[f][pf] + bias;
                    int pidx = pf*16 + lr + 1;
                    if (pidx >= 28) pidx = 29;
                    *((uint2*)&rec[par][prow][pidx][klocal]) = pack4(r);
                }
            }
        }

        // 4. deferred epilogue for strip s-1 (rec[(s-1)&1] stable: written pre-previous barrier)
        if (s > s0) { EPILOGUE(s-1) }

        // 5. ring write of prefetched group s+2 (slot (s+2)%4 disjoint from read slots)
        if (tid < 448) {
            asm volatile("s_waitcnt vmcnt(0)");
            __builtin_amdgcn_sched_barrier(0);
            uint2 u0 = pack4(ga0);
            int ar2 = 8*(s+2) + sr;
            *((uint2*)&ring[(ar2 & 31)*SCOLS + sc4*4]) = u0;
        }

        __syncthreads();   // single barrier: rec(s) ready for epi(s) @iter s+1; ring ready
    }

    // tail: epilogue for the last strip (rec written pre-final-barrier)
    EPILOGUE(s0 + 6)
#undef MSTEP
#undef MFMA2
#undef EPILOGUE
}

extern "C" void kernel_launch(void* const* d_in, const int* in_sizes, int n_in,
                              void* d_out, int out_size, void* d_ws, size_t ws_size,
                              hipStream_t stream) {
    (void)in_sizes; (void)n_in; (void)out_size; (void)ws_size;
    const float* x     = (const float*)d_in[0];
    const float* W_enc = (const float*)d_in[1];
    const float* b_enc = (const float*)d_in[2];
    const float* W_dec = (const float*)d_in[3];
    const float* b_dec = (const float*)d_in[4];
    float* out = (float*)d_out;

    float*          v   = (float*)d_ws;                          // 768 f32
    unsigned short* APK = (unsigned short*)((char*)d_ws + 4096); // 3 x 65536 bf16 = 384 KB

    pack_M<<<dim3(KK/2, 3), 256, 0, stream>>>(W_enc, W_dec, b_enc, b_dec, APK, v);
    patch_ae_loop<<<dim3(768), 512, 0, stream>>>(x, APK, v, out);
}